// Round 1
// baseline (882.442 us; speedup 1.0000x reference)
//
#include <hip/hip_runtime.h>

typedef _Float16 f16;
typedef _Float16 f16x8 __attribute__((ext_vector_type(8)));
typedef _Float16 f16x4 __attribute__((ext_vector_type(4)));
typedef float f32x4 __attribute__((ext_vector_type(4)));

#define MFMA16(a, b, c) __builtin_amdgcn_mfma_f32_16x16x32_f16((a), (b), (c), 0, 0, 0)

constexpr int DM = 1024;
constexpr int NH = 16;
constexpr int DEPTH = 64;
constexpr int SEQ = 2048;
constexpr int BATCH = 2;
constexpr int MTOT = BATCH * SEQ;  // 4096

// ---------------- fp32 -> fp16 convert ----------------
__global__ void k_cvt(const float* __restrict__ x, f16* __restrict__ y, int n) {
  int i = (blockIdx.x * blockDim.x + threadIdx.x) * 4;
  if (i >= n) return;
  const float4 v = *(const float4*)(x + i);
  f16x4 h;
  h[0] = (f16)v.x; h[1] = (f16)v.y; h[2] = (f16)v.z; h[3] = (f16)v.w;
  *(f16x4*)(y + i) = h;
}

// ---------------- GEMM: C[MTOTxDM] = A(f16) @ Bw(f32, cvt to f16) + bias ----------------
// MODE 0: out f16, split-head   [((b*16+h)*SEQ + s)*64 + d]   (Q, K)
// MODE 2: out f16, head-transp  [((b*16+h)*64 + d)*SEQ + s]   (V)
// MODE 1: out f32, row-major    [m*DM + n]                    (final projection)
template <int MODE>
__global__ __launch_bounds__(256) void k_gemm(const f16* __restrict__ A,
                                              const float* __restrict__ Bw,
                                              const float* __restrict__ bias,
                                              void* __restrict__ outp) {
  constexpr int K = DM, N = DM;
  __shared__ f16 Al[128 * 32];  // [m][k]
  __shared__ f16 Bl[128 * 32];  // [n][k]
  const int tid = threadIdx.x;
  const int lane = tid & 63;
  const int wave = tid >> 6;
  const int m0 = blockIdx.y * 128;
  const int n0 = blockIdx.x * 128;
  const int wr = (wave >> 1) * 64;
  const int wc = (wave & 1) * 64;
  const int lr = lane & 15;
  const int lk = (lane >> 4) * 8;

  f32x4 acc[4][4];
  for (int i = 0; i < 4; i++)
    for (int j = 0; j < 4; j++) acc[i][j] = (f32x4)0.0f;

  const int ar = tid >> 1, ak = (tid & 1) * 16;
  const int bn = (tid & 31) * 4, bk = (tid >> 5) * 4;

  for (int k0 = 0; k0 < K; k0 += 32) {
    __syncthreads();
    // stage A tile 128x32 (f16, 16 halves/thread)
    const f16* ag = A + (size_t)(m0 + ar) * K + k0 + ak;
    f16x8 a0 = *(const f16x8*)(ag);
    f16x8 a1 = *(const f16x8*)(ag + 8);
    *(f16x8*)(Al + ar * 32 + ak) = a0;
    *(f16x8*)(Al + ar * 32 + ak + 8) = a1;
    // stage B tile 32x128 fp32 -> transpose into Bl[n][k] as f16
    float4 w[4];
    for (int i = 0; i < 4; i++)
      w[i] = *(const float4*)(Bw + (size_t)(k0 + bk + i) * N + n0 + bn);
    for (int j = 0; j < 4; j++) {
      f16x4 h;
      h[0] = (f16)(((const float*)&w[0])[j]);
      h[1] = (f16)(((const float*)&w[1])[j]);
      h[2] = (f16)(((const float*)&w[2])[j]);
      h[3] = (f16)(((const float*)&w[3])[j]);
      *(f16x4*)(Bl + (size_t)(bn + j) * 32 + bk) = h;
    }
    __syncthreads();
    f16x8 af[4], bf[4];
    for (int i = 0; i < 4; i++)
      af[i] = *(const f16x8*)(Al + (wr + i * 16 + lr) * 32 + lk);
    for (int j = 0; j < 4; j++)
      bf[j] = *(const f16x8*)(Bl + (wc + j * 16 + lr) * 32 + lk);
    for (int i = 0; i < 4; i++)
      for (int j = 0; j < 4; j++) acc[i][j] = MFMA16(af[i], bf[j], acc[i][j]);
  }

  // epilogue: D[row=(lane>>4)*4+r][col=lane&15] (verified C/D layout)
  for (int j = 0; j < 4; j++) {
    const int n = n0 + wc + j * 16 + lr;
    const float bv = bias[n];
    for (int i = 0; i < 4; i++) {
      for (int r = 0; r < 4; r++) {
        const int m = m0 + wr + i * 16 + (lane >> 4) * 4 + r;
        const float val = acc[i][j][r] + bv;
        if (MODE == 1) {
          ((float*)outp)[(size_t)m * N + n] = val;
        } else {
          const int b = m >> 11, s = m & 2047;
          const int h = n >> 6, d = n & 63;
          size_t idx;
          if (MODE == 0)
            idx = ((size_t)(b * NH + h) * SEQ + s) * DEPTH + d;
          else
            idx = ((size_t)(b * NH + h) * DEPTH + d) * SEQ + s;
          ((f16*)outp)[idx] = (f16)val;
        }
      }
    }
  }
}

// ---------------- attention: logits -> softmax (2-pass, no max-sub) -> attn out + PV ----------------
__global__ __launch_bounds__(256) void k_attn(const f16* __restrict__ qws,
                                              const f16* __restrict__ kws,
                                              const f16* __restrict__ vtws,
                                              float* __restrict__ attn,
                                              f16* __restrict__ ctx) {
  __shared__ f16 Qs[64 * 64];      // [qrow][d]
  __shared__ f16 Ks[64 * 64];      // [key][d]
  __shared__ f16 Vs[64 * 64];      // [d][key]  (V pre-transposed in ws)
  __shared__ f16 Ps[4][16 * 64];   // per-wave P tile [qrow16][key64]

  const int tid = threadIdx.x, lane = tid & 63, wave = tid >> 6;
  const int bh = blockIdx.y;
  const int q0 = blockIdx.x * 64;
  const int lr = lane & 15, lk = (lane >> 4) * 8;

  const f16* qb = qws + (size_t)bh * SEQ * DEPTH;
  const f16* kb = kws + (size_t)bh * SEQ * DEPTH;
  const f16* vb = vtws + (size_t)bh * DEPTH * SEQ;

  const int sr = tid >> 2, sc = (tid & 3) * 16;
  *(f16x8*)(Qs + sr * 64 + sc)     = *(const f16x8*)(qb + (size_t)(q0 + sr) * 64 + sc);
  *(f16x8*)(Qs + sr * 64 + sc + 8) = *(const f16x8*)(qb + (size_t)(q0 + sr) * 64 + sc + 8);
  __syncthreads();
  // Q A-fragments (A[m=lane&15][k=(lane>>4)*8+j], verified layout), k-steps 0/1 over depth 64
  f16x8 qf0 = *(const f16x8*)(Qs + (wave * 16 + lr) * 64 + lk);
  f16x8 qf1 = *(const f16x8*)(Qs + (wave * 16 + lr) * 64 + 32 + lk);

  // ---- pass 1: row sums of exp(logit) ----
  float rs[4] = {0.f, 0.f, 0.f, 0.f};
  for (int kt = 0; kt < SEQ; kt += 64) {
    __syncthreads();
    *(f16x8*)(Ks + sr * 64 + sc)     = *(const f16x8*)(kb + (size_t)(kt + sr) * 64 + sc);
    *(f16x8*)(Ks + sr * 64 + sc + 8) = *(const f16x8*)(kb + (size_t)(kt + sr) * 64 + sc + 8);
    __syncthreads();
    for (int nb = 0; nb < 4; nb++) {
      f32x4 a = (f32x4)0.0f;
      f16x8 b0 = *(const f16x8*)(Ks + (nb * 16 + lr) * 64 + lk);
      f16x8 b1 = *(const f16x8*)(Ks + (nb * 16 + lr) * 64 + 32 + lk);
      a = MFMA16(qf0, b0, a);
      a = MFMA16(qf1, b1, a);
      for (int r = 0; r < 4; r++) rs[r] += __expf(a[r] * 0.125f);
    }
  }
  for (int r = 0; r < 4; r++) {
    float v = rs[r];
    v += __shfl_xor(v, 1);
    v += __shfl_xor(v, 2);
    v += __shfl_xor(v, 4);
    v += __shfl_xor(v, 8);
    rs[r] = 1.0f / v;
  }

  // ---- pass 2: recompute, write attn, fused PV ----
  f32x4 cacc[4];
  for (int d = 0; d < 4; d++) cacc[d] = (f32x4)0.0f;
  float* ab = attn + (size_t)bh * SEQ * SEQ;

  for (int kt = 0; kt < SEQ; kt += 64) {
    __syncthreads();
    *(f16x8*)(Ks + sr * 64 + sc)     = *(const f16x8*)(kb + (size_t)(kt + sr) * 64 + sc);
    *(f16x8*)(Ks + sr * 64 + sc + 8) = *(const f16x8*)(kb + (size_t)(kt + sr) * 64 + sc + 8);
    *(f16x8*)(Vs + sr * 64 + sc)     = *(const f16x8*)(vb + (size_t)sr * SEQ + kt + sc);
    *(f16x8*)(Vs + sr * 64 + sc + 8) = *(const f16x8*)(vb + (size_t)sr * SEQ + kt + sc + 8);
    __syncthreads();
    for (int nb = 0; nb < 4; nb++) {
      f32x4 a = (f32x4)0.0f;
      f16x8 b0 = *(const f16x8*)(Ks + (nb * 16 + lr) * 64 + lk);
      f16x8 b1 = *(const f16x8*)(Ks + (nb * 16 + lr) * 64 + 32 + lk);
      a = MFMA16(qf0, b0, a);
      a = MFMA16(qf1, b1, a);
      for (int r = 0; r < 4; r++) {
        const float p = __expf(a[r] * 0.125f) * rs[r];
        const int qrow = wave * 16 + (lane >> 4) * 4 + r;
        ab[(size_t)(q0 + qrow) * SEQ + kt + nb * 16 + lr] = p;
        Ps[wave][((lane >> 4) * 4 + r) * 64 + nb * 16 + lr] = (f16)p;
      }
    }
    __syncthreads();  // P C-layout -> A-layout via LDS round-trip
    for (int ks = 0; ks < 2; ks++) {
      f16x8 pf = *(const f16x8*)(Ps[wave] + lr * 64 + ks * 32 + lk);
      for (int d = 0; d < 4; d++) {
        f16x8 vf = *(const f16x8*)(Vs + (d * 16 + lr) * 64 + ks * 32 + lk);
        cacc[d] = MFMA16(pf, vf, cacc[d]);
      }
    }
  }

  // write ctx as f16 [b*SEQ+s][h*64+d] for the final projection GEMM
  const int b = bh >> 4, h = bh & 15;
  for (int d = 0; d < 4; d++) {
    for (int r = 0; r < 4; r++) {
      const int qrow = q0 + wave * 16 + (lane >> 4) * 4 + r;
      ctx[(size_t)(b * SEQ + qrow) * DM + h * DEPTH + d * 16 + lr] = (f16)cacc[d][r];
    }
  }
}

extern "C" void kernel_launch(void* const* d_in, const int* in_sizes, int n_in,
                              void* d_out, int out_size, void* d_ws, size_t ws_size,
                              hipStream_t stream) {
  const float* X  = (const float*)d_in[0];
  const float* wq = (const float*)d_in[1];
  const float* bq = (const float*)d_in[2];
  const float* wk = (const float*)d_in[3];
  const float* bk = (const float*)d_in[4];
  const float* wv = (const float*)d_in[5];
  const float* bv = (const float*)d_in[6];
  const float* wo = (const float*)d_in[7];
  const float* bo = (const float*)d_in[8];

  char* ws = (char*)d_ws;
  f16* Xh  = (f16*)(ws);
  f16* Qw  = (f16*)(ws + ((size_t)8 << 20));
  f16* Kw  = (f16*)(ws + ((size_t)16 << 20));
  f16* Vw  = (f16*)(ws + ((size_t)24 << 20));
  f16* Ctx = (f16*)(ws + ((size_t)32 << 20));

  float* out  = (float*)d_out;
  float* attn = out + (size_t)MTOT * DM;

  k_cvt<<<dim3(MTOT * DM / 1024), dim3(256), 0, stream>>>(X, Xh, MTOT * DM);
  dim3 gg(DM / 128, MTOT / 128);
  k_gemm<0><<<gg, 256, 0, stream>>>(Xh, wq, bq, (void*)Qw);
  k_gemm<0><<<gg, 256, 0, stream>>>(Xh, wk, bk, (void*)Kw);
  k_gemm<2><<<gg, 256, 0, stream>>>(Xh, wv, bv, (void*)Vw);
  k_attn<<<dim3(SEQ / 64, BATCH * NH), 256, 0, stream>>>(Qw, Kw, Vw, attn, Ctx);
  k_gemm<1><<<gg, 256, 0, stream>>>(Ctx, wo, bo, (void*)out);
}